// Round 11
// baseline (2339.999 us; speedup 1.0000x reference)
//
#include <hip/hip_runtime.h>
#include <stdint.h>
#include <stddef.h>

#define NTS 256

typedef short bf16x8 __attribute__((ext_vector_type(8)));
typedef float f32x4 __attribute__((ext_vector_type(4)));
typedef float f32x2 __attribute__((ext_vector_type(2)));
typedef float f32x16 __attribute__((ext_vector_type(16)));
typedef unsigned int u32x2 __attribute__((ext_vector_type(2)));

__device__ __forceinline__ unsigned short f2bf(float f) {
  union { float f; unsigned u; } c; c.f = f;
  unsigned u = c.u;
  u += 0x7fffu + ((u >> 16) & 1u);   // round-to-nearest-even (proven)
  return (unsigned short)(u >> 16);
}

// pack two f32 -> two bf16 (RNE; proven bit-compat with f2bf in r6/r7/r10)
__device__ __forceinline__ unsigned cvt_pk_bf16(float lo, float hi) {
  unsigned r;
  asm("v_cvt_pk_bf16_f32 %0, %1, %2" : "=v"(r) : "v"(lo), "v"(hi));
  return r;
}

// Fragment-ordered panels for 32x32x16 MFMA:
// wpF[pan(36)][fb(16)][lane(64)][e(8)] bf16
//   pan 0..3 -> W1 K-blocks (K=16 each), pan 4..35 -> W2 K-blocks
//   value = W[k = pank*16 + (lane>>5)*8 + e][f = fb*32 + (lane&31)]
__global__ __launch_bounds__(256) void prep_weights(const float* __restrict__ W1,
                                                    const float* __restrict__ W2,
                                                    unsigned short* __restrict__ wp) {
  int gid = blockIdx.x * 256 + threadIdx.x;
  if (gid >= 294912) return;
  int e = gid & 7, lane = (gid >> 3) & 63, fb = (gid >> 9) & 15, pan = gid >> 13;
  int k = (lane >> 5) * 8 + e, f = fb * 32 + (lane & 31);
  float v;
  if (pan < 4) v = W1[(pan * 16 + k) * 512 + f];
  else         v = W2[((pan - 4) * 16 + k) * 512 + f];
  wp[gid] = f2bf(v);
}

// LDS map (bytes):
//   [0,      65536)  w1L: W1 resident [pan(4)][fb(16)][lane(64)][16B]
//   [65536, 131072)  h1C [ks(32)][nt(2)][lane(64)][16B]  (B-frag order for L2)
//   [131072,139264)  histC [blk(8)=(ks(4),nt(2))][lane(64)][16B]
//   [139264,143360)  h0L u32[2][512] double-buffered elem-0 of each hist block
//   [143360,145408)  p0L f32[8][64]
//   [145408,147456)  p1L f32[8][64]
//   [147456,151552)  dwL f32[16][64]
//   [151552,153600)  b1L f32[512]
//   [153600,155648)  b2L f32[512]
//   [155648,159744)  w3L f32[512][2]
__global__ __launch_bounds__(512, 2) void po_fused(
    const float* __restrict__ dw, const float* __restrict__ x_init,
    const float* __restrict__ exp_arr, const float* __restrict__ b1,
    const float* __restrict__ b2, const float* __restrict__ W3,
    const float* __restrict__ b3, const unsigned short* __restrict__ wp,
    float* __restrict__ out) {
  extern __shared__ char smem[];
  char* const w1L = smem;
  char* const h1C = smem + 65536;
  char* const histC = smem + 131072;
  unsigned int* const h0L = (unsigned int*)(smem + 139264);
  float* const p0L = (float*)(smem + 143360);
  float* const p1L = (float*)(smem + 145408);
  float* const dwL = (float*)(smem + 147456);
  float* const b1L = (float*)(smem + 151552);
  float* const b2L = (float*)(smem + 153600);
  float* const w3L = (float*)(smem + 155648);

  const int tid = threadIdx.x;
  const int lane = tid & 63;
  const int wv = tid >> 6;          // 0..7
  const int hi = lane >> 5;         // K-half within fragment
  const int cl = lane & 31;         // column (batch) within 32-tile
  const int wg = blockIdx.x;

  // ---------------- init ----------------
  b1L[tid] = b1[tid];
  b2L[tid] = b2[tid];
  w3L[tid] = W3[tid];
  w3L[tid + 512] = W3[tid + 512];

  // hist block owned by this thread: block = wv -> (ks=wv>>1, nt=wv&1)
  const int b_col = (wv & 1) * 32 + cl;       // batch row of this thread's column
  {
    const int k0 = (wv >> 1) * 16 + hi * 8;
    const float* src = x_init + ((size_t)wg * 64 + b_col) * 64 + k0;
    bf16x8 v;
#pragma unroll
    for (int e = 0; e < 8; ++e) v[e] = (short)f2bf(src[e]);
    *(bf16x8*)(histC + tid * 16) = v;
    h0L[tid] = (unsigned int)(unsigned short)v[0];   // buffer 0 (read at t=0)
  }

  // replicated per-row dynamic state: row = lane (identical in all 8 waves)
  float xreg, yreg, rreg = 0.f;
  {
    const float* row = x_init + ((size_t)wg * 64 + lane) * 64;
    float y0 = 0.f;
    for (int k = 0; k < 63; ++k) y0 += exp_arr[k] * row[1 + k];
    yreg = y0 * 0.04f + (1.f - __expf(-2.52f)) * row[0];  // GEOMETRIC_SUM
    xreg = row[63];
  }
  const float b30 = b3[0], b31 = b3[1];

  // W1 -> LDS once (64KB, resident all 256 steps); linear DMA matches wp order
#pragma unroll
  for (int i = 0; i < 8; ++i) {
    const unsigned short* g = wp + i * 4096 + wv * 512 + lane * 8;
    char* l = w1L + i * 8192 + wv * 1024;  // HW adds lane*16
    __builtin_amdgcn_global_load_lds((const __attribute__((address_space(1))) void*)g,
                                     (__attribute__((address_space(3))) void*)l,
                                     16, 0, 0);
  }

  // W2 direct-load geometry (elements): panel stride 8192, frag = wfo + mt*512
  const unsigned short* const wpW2 = wp + 32768;
  const int wfo = wv * 1024 + lane * 8;

  // 4-buffer, 2-deep W2 register pipeline: w0..w3 <- panels 0..3
  bf16x8 w0[2], w1r[2], w2r[2], w3r[2];
#pragma unroll
  for (int mt = 0; mt < 2; ++mt) {
    w0[mt]  = *(const bf16x8*)(wpW2 + 0 * 8192 + wfo + mt * 512);
    w1r[mt] = *(const bf16x8*)(wpW2 + 1 * 8192 + wfo + mt * 512);
    w2r[mt] = *(const bf16x8*)(wpW2 + 2 * 8192 + wfo + mt * 512);
    w3r[mt] = *(const bf16x8*)(wpW2 + 3 * 8192 + wfo + mt * 512);
  }

  __syncthreads();   // drains W1 DMA + init LDS stores

  f32x16 acc[2][2];

  // One W2 phase: 2 B-frags, 4 MFMA(32x32x16), reload wreg (use->reload,
  // next use 3 phases later => ~380cy latency tolerance, wp is L2-resident)
  auto w2_phase = [&](bf16x8 (&wreg)[2], const char* h1b,
                      const unsigned short* wsrc) {
    bf16x8 bfr0 = *(const bf16x8*)(h1b + lane * 16);
    bf16x8 bfr1 = *(const bf16x8*)(h1b + 1024 + lane * 16);
    __builtin_amdgcn_s_setprio(1);
    acc[0][0] = __builtin_amdgcn_mfma_f32_32x32x16_bf16(wreg[0], bfr0, acc[0][0], 0, 0, 0);
    acc[0][1] = __builtin_amdgcn_mfma_f32_32x32x16_bf16(wreg[0], bfr1, acc[0][1], 0, 0, 0);
    acc[1][0] = __builtin_amdgcn_mfma_f32_32x32x16_bf16(wreg[1], bfr0, acc[1][0], 0, 0, 0);
    acc[1][1] = __builtin_amdgcn_mfma_f32_32x32x16_bf16(wreg[1], bfr1, acc[1][1], 0, 0, 0);
    __builtin_amdgcn_s_setprio(0);
    wreg[0] = *(const bf16x8*)(wsrc + wfo);
    wreg[1] = *(const bf16x8*)(wsrc + wfo + 512);
  };

#pragma unroll 1
  for (int t = 0; t < NTS; ++t) {
    // ---- dw tile staging every 16 steps ----
    if ((t & 15) == 0) {
      int b = tid >> 3, c = tid & 7;
      f32x2 v = *(const f32x2*)(dw + ((size_t)wg * 64 + b) * NTS + t + c * 2);
      dwL[(c * 2) * 64 + b] = v[0];
      dwL[(c * 2 + 1) * 64 + b] = v[1];
    }

    // ---- Layer 1: W1 (LDS) @ histT, K=64 in 4 panels ----
#pragma unroll
    for (int mt = 0; mt < 2; ++mt)
#pragma unroll
      for (int nt = 0; nt < 2; ++nt) acc[mt][nt] = (f32x16)(0.f);
#pragma unroll
    for (int p = 0; p < 4; ++p) {
      bf16x8 bfr[2];
#pragma unroll
      for (int nt = 0; nt < 2; ++nt)
        bfr[nt] = *(const bf16x8*)(histC + ((p * 2 + nt) * 64 + lane) * 16);
#pragma unroll
      for (int mt = 0; mt < 2; ++mt) {
        bf16x8 afr = *(const bf16x8*)(w1L + ((p * 16 + wv * 2 + mt) * 64 + lane) * 16);
#pragma unroll
        for (int nt = 0; nt < 2; ++nt)
          acc[mt][nt] = __builtin_amdgcn_mfma_f32_32x32x16_bf16(afr, bfr[nt],
                                                                acc[mt][nt], 0, 0, 0);
      }
    }
    // h1 epilogue: relu(+b1) -> bf16 -> h1C in B-frag order
    // C/D: col=cl, row = (reg&3) + 8*(reg>>2) + 4*hi ; f = (wv*2+mt)*32 + row
#pragma unroll
    for (int mt = 0; mt < 2; ++mt) {
      int fbase = (wv * 2 + mt) * 32 + 4 * hi;
#pragma unroll
      for (int r2 = 0; r2 < 4; ++r2) {
        int f0 = fbase + 8 * r2;
        f32x4 b1v = *(const f32x4*)(b1L + f0);
        int ks = (wv * 2 + mt) * 2 + (r2 >> 1);
        int lanep = cl + 32 * (r2 & 1);
        char* dst = h1C + ((ks * 2) * 64 + lanep) * 16 + hi * 8;
#pragma unroll
        for (int nt = 0; nt < 2; ++nt) {
          float v0 = fmaxf(acc[mt][nt][4 * r2 + 0] + b1v[0], 0.f);
          float v1 = fmaxf(acc[mt][nt][4 * r2 + 1] + b1v[1], 0.f);
          float v2 = fmaxf(acc[mt][nt][4 * r2 + 2] + b1v[2], 0.f);
          float v3 = fmaxf(acc[mt][nt][4 * r2 + 3] + b1v[3], 0.f);
          u32x2 pk;
          pk[0] = cvt_pk_bf16(v0, v1);
          pk[1] = cvt_pk_bf16(v2, v3);
          *(u32x2*)(dst + nt * 1024) = pk;
        }
      }
    }
    __syncthreads();  // (A) h1C + dwL visible

    // ---- Layer 2: 32 K-panels, 4-buffer 2-deep L2->VGPR pipeline ----
#pragma unroll
    for (int mt = 0; mt < 2; ++mt)
#pragma unroll
      for (int nt = 0; nt < 2; ++nt) acc[mt][nt] = (f32x16)(0.f);
    {
      const unsigned short* pb = wpW2;
      const char* h1p = h1C;
#pragma unroll 1
      for (int a = 0; a < 8; ++a) {
        const unsigned short* pn = (a == 7) ? wpW2 : (pb + 4 * 8192);
        w2_phase(w0,  h1p,        pn);
        w2_phase(w1r, h1p + 2048, pn + 8192);
        w2_phase(w2r, h1p + 4096, pn + 16384);
        w2_phase(w3r, h1p + 6144, pn + 24576);
        pb += 4 * 8192;
        h1p += 8192;
      }
    }

    // ---- Layer 3 folded: pi partials over this wave's f-slice ----
    {
      float p0a[2] = {0.f, 0.f};
      float p1a[2] = {0.f, 0.f};
#pragma unroll
      for (int mt = 0; mt < 2; ++mt) {
        int fbase = (wv * 2 + mt) * 32 + 4 * hi;
#pragma unroll
        for (int r2 = 0; r2 < 4; ++r2) {
          int f0 = fbase + 8 * r2;
          f32x4 b2v = *(const f32x4*)(b2L + f0);
          f32x4 w3a = *(const f32x4*)(w3L + f0 * 2);
          f32x4 w3b = *(const f32x4*)(w3L + f0 * 2 + 4);
#pragma unroll
          for (int nt = 0; nt < 2; ++nt) {
            float v0 = fmaxf(acc[mt][nt][4 * r2 + 0] + b2v[0], 0.f);
            float v1 = fmaxf(acc[mt][nt][4 * r2 + 1] + b2v[1], 0.f);
            float v2 = fmaxf(acc[mt][nt][4 * r2 + 2] + b2v[2], 0.f);
            float v3 = fmaxf(acc[mt][nt][4 * r2 + 3] + b2v[3], 0.f);
            p0a[nt] += v0 * w3a[0] + v1 * w3a[2] + v2 * w3b[0] + v3 * w3b[2];
            p1a[nt] += v0 * w3a[1] + v1 * w3a[3] + v2 * w3b[1] + v3 * w3b[3];
          }
        }
      }
#pragma unroll
      for (int nt = 0; nt < 2; ++nt) {
        p0a[nt] += __shfl_xor(p0a[nt], 32);
        p1a[nt] += __shfl_xor(p1a[nt], 32);
        if (hi == 0) {
          p0L[wv * 64 + nt * 32 + cl] = p0a[nt];
          p1L[wv * 64 + nt * 32 + cl] = p1a[nt];
        }
      }
    }
    __syncthreads();  // (B) p0L/p1L visible

    // ---- dynamics: replicated on ALL waves (row = lane) ----
    float xn;
    {
      float z0 = b30, z1 = b31;
#pragma unroll
      for (int w = 0; w < 8; ++w) {
        z0 += p0L[w * 64 + lane];
        z1 += p1L[w * 64 + lane];
      }
      float pi0 = 2.f / (1.f + __expf(-z0));
      float pi1 = 2.f / (1.f + __expf(-z1));
      float x = xreg, y = yreg;
      float disc = __expf(-0.004f * (float)t);         // exp(-BETA*DT*t)
      float rv = fmaxf(pi0 * x, 0.f) + 1e-6f;
      rreg += (__logf(rv) * disc - fmaxf(-x, 0.f) * 100.f) * 0.04f;
      float dwv = dwL[(t & 15) * 64 + lane];
      float dxv = (0.06f * pi1 - pi0 + 0.02f) * x + 0.02f * y;
      xn = x + dxv * 0.04f + 0.2f * x * pi1 * dwv;
      yreg = y * 0.960789439152323f + xn * 0.04f;      // exp(-DT*LAMBD)
      xreg = xn;
    }

    // ---- hist shift: all shuffles uniform (exec-mask-safe), then select ----
    // thread block (ks=wv>>1, nt=wv&1), k = ks*16 + hi*8 + e
    {
      bf16x8 own = *(const bf16x8*)(histC + tid * 16);
      int e0 = (int)(unsigned short)own[0];
      int nbr = __shfl_down(e0, 32);          // elem0 of hi=1 half, same block
      float xb = __shfl(xn, b_col);           // uniform all-lane shuffle
      unsigned short xbf = f2bf(xb);
      unsigned short last;
      if (hi == 1) {
        // k+1 = (ks+1)*16 -> block wv+2's hi=0 elem0, unless ks==3 -> x_new
        last = (wv >= 6) ? xbf
                         : (unsigned short)h0L[(t & 1) * 512 + (wv + 2) * 64 + cl];
      } else {
        last = (unsigned short)nbr;
      }
      bf16x8 nw;
#pragma unroll
      for (int e = 0; e < 7; ++e) nw[e] = own[e + 1];
      nw[7] = (short)last;
      *(bf16x8*)(histC + tid * 16) = nw;
      h0L[((t + 1) & 1) * 512 + tid] = (unsigned int)(unsigned short)nw[0];
    }
    __syncthreads();  // (C) histC + h0L stable for next step
  }

  if (tid < 64) {
    float rw = rreg + __logf(fmaxf(xreg + 0.5f * yreg, 0.f) + 1e-6f) * 10.f * __expf(-1.024f);
    rw -= fmaxf(-xreg, 0.f) * 100.f;
    out[(size_t)wg * 64 + tid] = -rw;
  }
}

extern "C" void kernel_launch(void* const* d_in, const int* in_sizes, int n_in,
                              void* d_out, int out_size, void* d_ws, size_t ws_size,
                              hipStream_t stream) {
  const float* dw      = (const float*)d_in[0];
  const float* x_init  = (const float*)d_in[1];
  const float* exp_arr = (const float*)d_in[2];
  const float* W1      = (const float*)d_in[3];
  const float* b1      = (const float*)d_in[4];
  const float* W2      = (const float*)d_in[5];
  const float* b2      = (const float*)d_in[6];
  const float* W3      = (const float*)d_in[7];
  const float* b3      = (const float*)d_in[8];
  unsigned short* wp = (unsigned short*)d_ws;  // needs 576KB
  float* out = (float*)d_out;

  (void)hipFuncSetAttribute((const void*)po_fused,
                            hipFuncAttributeMaxDynamicSharedMemorySize, 160 * 1024);

  prep_weights<<<1152, 256, 0, stream>>>(W1, W2, wp);
  po_fused<<<256, 512, 159744, stream>>>(dw, x_init, exp_arr, b1, b2, W3, b3, wp, out);
}